// Round 5
// baseline (531.752 us; speedup 1.0000x reference)
//
#include <hip/hip_runtime.h>

#define NN 100000
#define NE 3200000
#define CC 256
#define NEG_SLOPE 0.2f

#define NBLK 256
#define NTHR 1024
#define NTOT (NBLK * NTHR)      // 262144
#define NWAVES (NTOT / 64)      // 4096
#define SEG_S 32                // edge slices
#define SEG_P 8                 // node partitions
#define PART_SZ 12500           // NN / SEG_P -> 50 KB LDS
#define ESLICE (NE / SEG_S)     // 100000 edges/slice

typedef __attribute__((ext_vector_type(8))) _Float16 half8;

// Device-wide arrive-and-wait barrier. Safe: grid=256 blocks, each CU can
// host >=1 (16 waves, 50KB LDS, <=128 VGPR) -> all blocks co-resident.
// Release fence (L2 writeback) before arrival; acquire spin + fence after.
__device__ __forceinline__ void grid_barrier(unsigned* cnt, unsigned target) {
  __syncthreads();
  if (threadIdx.x == 0) {
    __threadfence();  // agent release: drains + writes back this XCD's L2
    __hip_atomic_fetch_add(cnt, 1u, __ATOMIC_RELEASE, __HIP_MEMORY_SCOPE_AGENT);
    while (__hip_atomic_load(cnt, __ATOMIC_ACQUIRE, __HIP_MEMORY_SCOPE_AGENT) < target) {
      __builtin_amdgcn_s_sleep(2);
    }
    __threadfence();  // acquire: invalidate stale L1/L2 lines
  }
  __syncthreads();
}

__global__ __launch_bounds__(NTHR, 4) void gat_mono_kernel(
    const float* __restrict__ x,
    const float* __restrict__ att,
    const int* __restrict__ row,
    const int* __restrict__ col,
    float* __restrict__ s_src,
    float* __restrict__ s_dst,
    float* __restrict__ rdenom,
    _Float16* __restrict__ e_buf,
    float* __restrict__ partial,
    unsigned* __restrict__ barriers,
    float4* __restrict__ out4) {
  __shared__ float tile[PART_SZ];
  const int tid  = threadIdx.x;
  const int gtid = blockIdx.x * NTHR + tid;

  // ---- Phase 1: per-node dual dot products (wave-per-node, grid-stride) ----
  {
    int wave = gtid >> 6;
    int lane = tid & 63;
    float4 av = ((const float4*)att)[lane];         // att[:C], hoisted
    float4 bv = ((const float4*)(att + CC))[lane];  // att[C:]
    for (int node = wave; node < NN; node += NWAVES) {
      float4 xv = ((const float4*)(x + (size_t)node * CC))[lane];
      float s0 = xv.x * av.x + xv.y * av.y + xv.z * av.z + xv.w * av.w;
      float s1 = xv.x * bv.x + xv.y * bv.y + xv.z * bv.z + xv.w * bv.w;
#pragma unroll
      for (int off = 32; off > 0; off >>= 1) {
        s0 += __shfl_down(s0, off, 64);
        s1 += __shfl_down(s1, off, 64);
      }
      if (lane == 0) { s_src[node] = s0; s_dst[node] = s1; }
    }
  }
  grid_barrier(barriers + 0, NBLK);

  // ---- Phase 2: edge scores -> leaky_relu -> exp -> e (f16), 8/thread ----
  // Softmax max-subtraction cancels algebraically; exp(alpha) in fp16 range.
  {
    const int4* row4 = (const int4*)row;
    const int4* col4 = (const int4*)col;
    for (int i = gtid; i < NE / 8; i += NTOT) {
      int4 ra = row4[2 * i], rb = row4[2 * i + 1];
      int4 ca = col4[2 * i], cb = col4[2 * i + 1];
      float a0 = s_src[ra.x] + s_dst[ca.x];
      float a1 = s_src[ra.y] + s_dst[ca.y];
      float a2 = s_src[ra.z] + s_dst[ca.z];
      float a3 = s_src[ra.w] + s_dst[ca.w];
      float a4 = s_src[rb.x] + s_dst[cb.x];
      float a5 = s_src[rb.y] + s_dst[cb.y];
      float a6 = s_src[rb.z] + s_dst[cb.z];
      float a7 = s_src[rb.w] + s_dst[cb.w];
      a0 = (a0 > 0.0f) ? a0 : NEG_SLOPE * a0;
      a1 = (a1 > 0.0f) ? a1 : NEG_SLOPE * a1;
      a2 = (a2 > 0.0f) ? a2 : NEG_SLOPE * a2;
      a3 = (a3 > 0.0f) ? a3 : NEG_SLOPE * a3;
      a4 = (a4 > 0.0f) ? a4 : NEG_SLOPE * a4;
      a5 = (a5 > 0.0f) ? a5 : NEG_SLOPE * a5;
      a6 = (a6 > 0.0f) ? a6 : NEG_SLOPE * a6;
      a7 = (a7 > 0.0f) ? a7 : NEG_SLOPE * a7;
      half8 h;
      h[0] = (_Float16)__expf(a0);
      h[1] = (_Float16)__expf(a1);
      h[2] = (_Float16)__expf(a2);
      h[3] = (_Float16)__expf(a3);
      h[4] = (_Float16)__expf(a4);
      h[5] = (_Float16)__expf(a5);
      h[6] = (_Float16)__expf(a6);
      h[7] = (_Float16)__expf(a7);
      ((half8*)e_buf)[i] = h;
    }
  }
  grid_barrier(barriers + 1, NBLK);

  // ---- Phase 3: atomic-free segment sum. Block (s,p): stream slice s,
  // LDS-add rows in partition p, write NON-atomic partial tile.
  // s = blk&31 keeps slice-siblings == s (mod 8) -> same XCD -> L2-shared.
  {
    int s = blockIdx.x & (SEG_S - 1);
    int p = blockIdx.x >> 5;
    for (int i = tid; i < PART_SZ; i += NTHR) tile[i] = 0.0f;
    __syncthreads();
    int lo = p * PART_SZ;
    const int4*  row4s = (const int4*)(row + s * ESLICE);
    const half8* e8    = (const half8*)(e_buf + (size_t)s * ESLICE);
    for (int i = tid; i < ESLICE / 8; i += NTHR) {
      int4 ra = row4s[2 * i], rb = row4s[2 * i + 1];
      half8 ev = e8[i];
      int r0 = ra.x - lo; if ((unsigned)r0 < PART_SZ) atomicAdd(&tile[r0], (float)ev[0]);
      int r1 = ra.y - lo; if ((unsigned)r1 < PART_SZ) atomicAdd(&tile[r1], (float)ev[1]);
      int r2 = ra.z - lo; if ((unsigned)r2 < PART_SZ) atomicAdd(&tile[r2], (float)ev[2]);
      int r3 = ra.w - lo; if ((unsigned)r3 < PART_SZ) atomicAdd(&tile[r3], (float)ev[3]);
      int r4 = rb.x - lo; if ((unsigned)r4 < PART_SZ) atomicAdd(&tile[r4], (float)ev[4]);
      int r5 = rb.y - lo; if ((unsigned)r5 < PART_SZ) atomicAdd(&tile[r5], (float)ev[5]);
      int r6 = rb.z - lo; if ((unsigned)r6 < PART_SZ) atomicAdd(&tile[r6], (float)ev[6]);
      int r7 = rb.w - lo; if ((unsigned)r7 < PART_SZ) atomicAdd(&tile[r7], (float)ev[7]);
    }
    __syncthreads();
    float* outp = partial + (size_t)s * NN + lo;
    for (int i = tid; i < PART_SZ; i += NTHR) outp[i] = tile[i];
  }
  grid_barrier(barriers + 2, NBLK);

  // ---- Phase 4: fold 32 slice-partials, store reciprocal ----
  {
    for (int n4 = gtid; n4 < NN / 4; n4 += NTOT) {
      float4 sum = make_float4(0.f, 0.f, 0.f, 0.f);
#pragma unroll
      for (int s2 = 0; s2 < SEG_S; ++s2) {
        float4 v = ((const float4*)(partial + (size_t)s2 * NN))[n4];
        sum.x += v.x; sum.y += v.y; sum.z += v.z; sum.w += v.w;
      }
      ((float4*)rdenom)[n4] =
          make_float4(1.f / sum.x, 1.f / sum.y, 1.f / sum.z, 1.f / sum.w);
    }
  }
  grid_barrier(barriers + 3, NBLK);

  // ---- Phase 5: normalize, 8 edges/thread, fp32 out ----
  {
    const int4*  row4 = (const int4*)row;
    const half8* e8   = (const half8*)e_buf;
    for (int i = gtid; i < NE / 8; i += NTOT) {
      int4 ra = row4[2 * i], rb = row4[2 * i + 1];
      half8 ev = e8[i];
      float4 oa, ob;
      oa.x = (float)ev[0] * rdenom[ra.x];
      oa.y = (float)ev[1] * rdenom[ra.y];
      oa.z = (float)ev[2] * rdenom[ra.z];
      oa.w = (float)ev[3] * rdenom[ra.w];
      ob.x = (float)ev[4] * rdenom[rb.x];
      ob.y = (float)ev[5] * rdenom[rb.y];
      ob.z = (float)ev[6] * rdenom[rb.z];
      ob.w = (float)ev[7] * rdenom[rb.w];
      out4[2 * i]     = oa;
      out4[2 * i + 1] = ob;
    }
  }
}

extern "C" void kernel_launch(void* const* d_in, const int* in_sizes, int n_in,
                              void* d_out, int out_size, void* d_ws, size_t ws_size,
                              hipStream_t stream) {
  const float* x   = (const float*)d_in[0];
  const float* att = (const float*)d_in[1];
  const int* ei    = (const int*)d_in[2];  // (2, E): row then col
  const int* row   = ei;
  const int* col   = ei + NE;
  float4* out4     = (float4*)d_out;  // E floats, final output

  // Workspace layout (16B-aligned throughout):
  unsigned* barriers = (unsigned*)d_ws;               // 64 uints (4 used)
  float* s_src       = (float*)d_ws + 64;             // N f32
  float* s_dst       = s_src + NN;                    // N f32
  float* rdenom      = s_dst + NN;                    // N f32
  float* partial     = rdenom + NN;                   // SEG_S*N f32 (12.8 MB)
  _Float16* e_buf    = (_Float16*)(partial + (size_t)SEG_S * NN);  // E f16

  hipMemsetAsync(d_ws, 0, 64 * sizeof(unsigned), stream);  // zero barrier counters
  gat_mono_kernel<<<NBLK, NTHR, 0, stream>>>(
      x, att, row, col, s_src, s_dst, rdenom, e_buf, partial, barriers, out4);
}

// Round 6
// 488.482 us; speedup vs baseline: 1.0886x; 1.0886x over previous
//
#include <hip/hip_runtime.h>

#define NN 100000
#define NE 3200000
#define CC 256
#define NEG_SLOPE 0.2f

#define NBLK 512
#define NTHR 1024
#define NTOT (NBLK * NTHR)      // 524288
#define NWAVES (NTOT / 64)      // 8192
#define SEG_S 64                // edge slices
#define SEG_P 8                 // node partitions
#define PART_SZ 12500           // NN / SEG_P -> 50 KB LDS
#define ESLICE (NE / SEG_S)     // 50000 edges/slice

typedef __attribute__((ext_vector_type(8))) _Float16 half8;

// Device-wide arrive-and-wait barrier.
// Co-residency: 512 blocks, 2/CU (2x50KB LDS <= 160KB, 32 waves/CU, VGPR<=64).
// KEY FIX vs R5: poll with a RELAXED fetch_add(0) — an RMW executes at the
// coherence point (R2 measured: fp32 atomic RMWs bypass L2), so it sees
// remote arrivals WITHOUT the per-poll buffer_inv an ACQUIRE load emits.
// R5's acquire-poll invalidated L2 every ~128cyc on all XCDs = thrash storm.
__device__ __forceinline__ void grid_barrier(unsigned* cnt, unsigned target) {
  __syncthreads();
  if (threadIdx.x == 0) {
    __threadfence();  // release: make prior writes device-visible
    __hip_atomic_fetch_add(cnt, 1u, __ATOMIC_RELAXED, __HIP_MEMORY_SCOPE_AGENT);
    while (__hip_atomic_fetch_add(cnt, 0u, __ATOMIC_RELAXED,
                                  __HIP_MEMORY_SCOPE_AGENT) < target) {
      __builtin_amdgcn_s_sleep(4);
    }
    __threadfence();  // acquire: ONE cache-inv per block, after exit
  }
  __syncthreads();
}

__global__ __launch_bounds__(NTHR, 8) void gat_mono_kernel(
    const float* __restrict__ x,
    const float* __restrict__ att,
    const int* __restrict__ row,
    const int* __restrict__ col,
    float* __restrict__ s_src,
    float* __restrict__ s_dst,
    float* __restrict__ rdenom,
    _Float16* __restrict__ e_buf,
    float* __restrict__ partial,
    unsigned* __restrict__ barriers,
    float4* __restrict__ out4) {
  __shared__ float tile[PART_SZ];
  const int tid  = threadIdx.x;
  const int gtid = blockIdx.x * NTHR + tid;

  // ---- Phase 1: per-node dual dot products (wave-per-node, grid-stride) ----
  {
    int wave = gtid >> 6;
    int lane = tid & 63;
    float4 av = ((const float4*)att)[lane];         // att[:C]
    float4 bv = ((const float4*)(att + CC))[lane];  // att[C:]
    for (int node = wave; node < NN; node += NWAVES) {
      float4 xv = ((const float4*)(x + (size_t)node * CC))[lane];
      float s0 = xv.x * av.x + xv.y * av.y + xv.z * av.z + xv.w * av.w;
      float s1 = xv.x * bv.x + xv.y * bv.y + xv.z * bv.z + xv.w * bv.w;
#pragma unroll
      for (int off = 32; off > 0; off >>= 1) {
        s0 += __shfl_down(s0, off, 64);
        s1 += __shfl_down(s1, off, 64);
      }
      if (lane == 0) { s_src[node] = s0; s_dst[node] = s1; }
    }
  }
  grid_barrier(barriers + 0, NBLK);

  // ---- Phase 2: edge scores -> leaky_relu -> exp -> e (f16), 8/thread ----
  // Softmax max-subtraction cancels algebraically; exp(alpha) fits fp16.
  {
    const int4* row4 = (const int4*)row;
    const int4* col4 = (const int4*)col;
    for (int i = gtid; i < NE / 8; i += NTOT) {
      int4 ra = row4[2 * i], rb = row4[2 * i + 1];
      int4 ca = col4[2 * i], cb = col4[2 * i + 1];
      float a0 = s_src[ra.x] + s_dst[ca.x];
      float a1 = s_src[ra.y] + s_dst[ca.y];
      float a2 = s_src[ra.z] + s_dst[ca.z];
      float a3 = s_src[ra.w] + s_dst[ca.w];
      float a4 = s_src[rb.x] + s_dst[cb.x];
      float a5 = s_src[rb.y] + s_dst[cb.y];
      float a6 = s_src[rb.z] + s_dst[cb.z];
      float a7 = s_src[rb.w] + s_dst[cb.w];
      a0 = (a0 > 0.0f) ? a0 : NEG_SLOPE * a0;
      a1 = (a1 > 0.0f) ? a1 : NEG_SLOPE * a1;
      a2 = (a2 > 0.0f) ? a2 : NEG_SLOPE * a2;
      a3 = (a3 > 0.0f) ? a3 : NEG_SLOPE * a3;
      a4 = (a4 > 0.0f) ? a4 : NEG_SLOPE * a4;
      a5 = (a5 > 0.0f) ? a5 : NEG_SLOPE * a5;
      a6 = (a6 > 0.0f) ? a6 : NEG_SLOPE * a6;
      a7 = (a7 > 0.0f) ? a7 : NEG_SLOPE * a7;
      half8 h;
      h[0] = (_Float16)__expf(a0);
      h[1] = (_Float16)__expf(a1);
      h[2] = (_Float16)__expf(a2);
      h[3] = (_Float16)__expf(a3);
      h[4] = (_Float16)__expf(a4);
      h[5] = (_Float16)__expf(a5);
      h[6] = (_Float16)__expf(a6);
      h[7] = (_Float16)__expf(a7);
      ((half8*)e_buf)[i] = h;
    }
  }
  grid_barrier(barriers + 1, NBLK);

  // ---- Phase 3: atomic-free segment sum. Block (s,p): stream slice s,
  // LDS-add rows in partition p, write NON-atomic partial tile.
  // s = blk&63: slice-siblings are == s (mod 8) -> same XCD -> the 8x
  // slice re-read stays in that XCD's L2 (slice = 200KB row + 100KB e).
  {
    int s = blockIdx.x & (SEG_S - 1);
    int p = blockIdx.x >> 6;
    for (int i = tid; i < PART_SZ; i += NTHR) tile[i] = 0.0f;
    __syncthreads();
    int lo = p * PART_SZ;
    const int4*  row4s = (const int4*)(row + s * ESLICE);
    const half8* e8    = (const half8*)(e_buf + (size_t)s * ESLICE);
    for (int i = tid; i < ESLICE / 8; i += NTHR) {
      int4 ra = row4s[2 * i], rb = row4s[2 * i + 1];
      half8 ev = e8[i];
      int r0 = ra.x - lo; if ((unsigned)r0 < PART_SZ) atomicAdd(&tile[r0], (float)ev[0]);
      int r1 = ra.y - lo; if ((unsigned)r1 < PART_SZ) atomicAdd(&tile[r1], (float)ev[1]);
      int r2 = ra.z - lo; if ((unsigned)r2 < PART_SZ) atomicAdd(&tile[r2], (float)ev[2]);
      int r3 = ra.w - lo; if ((unsigned)r3 < PART_SZ) atomicAdd(&tile[r3], (float)ev[3]);
      int r4 = rb.x - lo; if ((unsigned)r4 < PART_SZ) atomicAdd(&tile[r4], (float)ev[4]);
      int r5 = rb.y - lo; if ((unsigned)r5 < PART_SZ) atomicAdd(&tile[r5], (float)ev[5]);
      int r6 = rb.z - lo; if ((unsigned)r6 < PART_SZ) atomicAdd(&tile[r6], (float)ev[6]);
      int r7 = rb.w - lo; if ((unsigned)r7 < PART_SZ) atomicAdd(&tile[r7], (float)ev[7]);
    }
    __syncthreads();
    float* outp = partial + (size_t)s * NN + lo;
    for (int i = tid; i < PART_SZ; i += NTHR) outp[i] = tile[i];
  }
  grid_barrier(barriers + 2, NBLK);

  // ---- Phase 4: fold 64 slice-partials, store reciprocal ----
  {
    for (int n4 = gtid; n4 < NN / 4; n4 += NTOT) {
      float4 sum = make_float4(0.f, 0.f, 0.f, 0.f);
#pragma unroll
      for (int s2 = 0; s2 < SEG_S; ++s2) {
        float4 v = ((const float4*)(partial + (size_t)s2 * NN))[n4];
        sum.x += v.x; sum.y += v.y; sum.z += v.z; sum.w += v.w;
      }
      ((float4*)rdenom)[n4] =
          make_float4(1.f / sum.x, 1.f / sum.y, 1.f / sum.z, 1.f / sum.w);
    }
  }
  grid_barrier(barriers + 3, NBLK);

  // ---- Phase 5: normalize, 8 edges/thread, fp32 out ----
  {
    const int4*  row4 = (const int4*)row;
    const half8* e8   = (const half8*)e_buf;
    for (int i = gtid; i < NE / 8; i += NTOT) {
      int4 ra = row4[2 * i], rb = row4[2 * i + 1];
      half8 ev = e8[i];
      float4 oa, ob;
      oa.x = (float)ev[0] * rdenom[ra.x];
      oa.y = (float)ev[1] * rdenom[ra.y];
      oa.z = (float)ev[2] * rdenom[ra.z];
      oa.w = (float)ev[3] * rdenom[ra.w];
      ob.x = (float)ev[4] * rdenom[rb.x];
      ob.y = (float)ev[5] * rdenom[rb.y];
      ob.z = (float)ev[6] * rdenom[rb.z];
      ob.w = (float)ev[7] * rdenom[rb.w];
      out4[2 * i]     = oa;
      out4[2 * i + 1] = ob;
    }
  }
}

extern "C" void kernel_launch(void* const* d_in, const int* in_sizes, int n_in,
                              void* d_out, int out_size, void* d_ws, size_t ws_size,
                              hipStream_t stream) {
  const float* x   = (const float*)d_in[0];
  const float* att = (const float*)d_in[1];
  const int* ei    = (const int*)d_in[2];  // (2, E): row then col
  const int* row   = ei;
  const int* col   = ei + NE;
  float4* out4     = (float4*)d_out;  // E floats, final output

  // Workspace layout (16B-aligned throughout):
  unsigned* barriers = (unsigned*)d_ws;               // 64 uints (4 used)
  float* s_src       = (float*)d_ws + 64;             // N f32
  float* s_dst       = s_src + NN;                    // N f32
  float* rdenom      = s_dst + NN;                    // N f32
  float* partial     = rdenom + NN;                   // SEG_S*N f32 (25.6 MB)
  _Float16* e_buf    = (_Float16*)(partial + (size_t)SEG_S * NN);  // E f16

  hipMemsetAsync(d_ws, 0, 64 * sizeof(unsigned), stream);  // zero barrier counters
  gat_mono_kernel<<<NBLK, NTHR, 0, stream>>>(
      x, att, row, col, s_src, s_dst, rdenom, e_buf, partial, barriers, out4);
}

// Round 8
// 244.143 us; speedup vs baseline: 2.1780x; 2.0008x over previous
//
#include <hip/hip_runtime.h>

#define NN 100000
#define NE 3200000
#define CC 256
#define NEG_SLOPE 0.2f

#define SEG_S 32             // edge slices (non-atomic partials)
#define SEG_P 8              // node partitions
#define PART_SZ 12500        // NN / SEG_P -> 50 KB LDS
#define SEG_BLOCK 1024
#define ESLICE (NE / SEG_S)  // 100000 edges per slice

typedef __attribute__((ext_vector_type(4))) float f32x4;  // true vector type
                                                          // (nontemporal builtin
                                                          // rejects HIP float4)

// Kernel A: per-node dual dot products. One wave per node iteration,
// grid-stride so att fragments are loaded once per wave, not per node.
// nsr[n].x = s_src[n] (y filled later by reduce with 1/denom).
__global__ __launch_bounds__(256) void node_scores_kernel(
    const float* __restrict__ x,
    const float* __restrict__ att,
    float2* __restrict__ nsr,
    float* __restrict__ s_dst) {
  int wave = (blockIdx.x * blockDim.x + threadIdx.x) >> 6;
  int lane = threadIdx.x & 63;
  const int nwaves = (gridDim.x * blockDim.x) >> 6;
  float4 av = ((const float4*)att)[lane];         // att[:C]
  float4 bv = ((const float4*)(att + CC))[lane];  // att[C:]
  for (int node = wave; node < NN; node += nwaves) {
    float4 xv = ((const float4*)(x + (size_t)node * CC))[lane];
    float s0 = xv.x * av.x + xv.y * av.y + xv.z * av.z + xv.w * av.w;
    float s1 = xv.x * bv.x + xv.y * bv.y + xv.z * bv.z + xv.w * bv.w;
#pragma unroll
    for (int off = 32; off > 0; off >>= 1) {
      s0 += __shfl_down(s0, off, 64);
      s1 += __shfl_down(s1, off, 64);
    }
    if (lane == 0) {
      nsr[node].x = s0;
      s_dst[node] = s1;
    }
  }
}

// Kernel B: fused exp + atomic-free segment sum. Block (s,p) streams the
// row AND col of slice s (coalesced int4; L2-captured across the 8
// siblings, which land on the same XCD since linear id = s+32p == s mod 8),
// and for edges whose row is in partition p (exec-predicated, so each
// edge's gathers+exp run exactly once chip-wide) computes
// exp(leaky_relu(s_src[r]+s_dst[c])) and LDS-adds it. Tile written as a
// NON-atomic partial. No e-buffer round trip at all.
__global__ __launch_bounds__(SEG_BLOCK) void segsum_kernel(
    const int* __restrict__ row,
    const int* __restrict__ col,
    const float2* __restrict__ nsr,
    const float* __restrict__ s_dst,
    float* __restrict__ partial /* [SEG_S][NN] */) {
  __shared__ float tile[PART_SZ];
  const int s = blockIdx.x;  // slice (fastest -> siblings co-XCD)
  const int p = blockIdx.y;  // node partition
  for (int i = threadIdx.x; i < PART_SZ; i += SEG_BLOCK) tile[i] = 0.0f;
  __syncthreads();
  const int lo = p * PART_SZ;
  const float* srcf = (const float*)nsr;  // s_src[n] at index 2n
  const int4* row4s = (const int4*)(row + s * ESLICE);
  const int4* col4s = (const int4*)(col + s * ESLICE);
  for (int i = threadIdx.x; i < ESLICE / 8; i += SEG_BLOCK) {
    int4 ra = row4s[2 * i], rb = row4s[2 * i + 1];
    int4 ca = col4s[2 * i], cb = col4s[2 * i + 1];
#define SEG_ONE(r, c)                                         \
    {                                                         \
      int rr = (r) - lo;                                      \
      if ((unsigned)rr < PART_SZ) {                           \
        float a = srcf[2 * (r)] + s_dst[(c)];                 \
        a = (a > 0.0f) ? a : NEG_SLOPE * a;                   \
        atomicAdd(&tile[rr], __expf(a));                      \
      }                                                       \
    }
    SEG_ONE(ra.x, ca.x) SEG_ONE(ra.y, ca.y)
    SEG_ONE(ra.z, ca.z) SEG_ONE(ra.w, ca.w)
    SEG_ONE(rb.x, cb.x) SEG_ONE(rb.y, cb.y)
    SEG_ONE(rb.z, cb.z) SEG_ONE(rb.w, cb.w)
#undef SEG_ONE
  }
  __syncthreads();
  float* outp = partial + (size_t)s * NN + lo;
  for (int i = threadIdx.x; i < PART_SZ; i += SEG_BLOCK) outp[i] = tile[i];
}

// Kernel C: fold 32 slice-partials (float4 reads), store 1/denom into
// nsr[n].y so kernel D gathers {s_src, rdenom} with ONE 8B load per edge.
__global__ __launch_bounds__(256) void reduce_kernel(
    const float* __restrict__ partial,
    float2* __restrict__ nsr) {
  int n4 = blockIdx.x * blockDim.x + threadIdx.x;
  if (n4 >= NN / 4) return;
  float4 sum = make_float4(0.f, 0.f, 0.f, 0.f);
#pragma unroll
  for (int s = 0; s < SEG_S; ++s) {
    float4 v = ((const float4*)(partial + (size_t)s * NN))[n4];
    sum.x += v.x; sum.y += v.y; sum.z += v.z; sum.w += v.w;
  }
  int n = 4 * n4;
  nsr[n + 0].y = 1.0f / sum.x;
  nsr[n + 1].y = 1.0f / sum.y;
  nsr[n + 2].y = 1.0f / sum.z;
  nsr[n + 3].y = 1.0f / sum.w;
}

// Kernel D: 8 edges/thread: recompute exp from gathered scores and
// normalize. out never re-read -> nontemporal store.
__global__ __launch_bounds__(256) void edge_out_kernel(
    const int4* __restrict__ row4,
    const int4* __restrict__ col4,
    const float2* __restrict__ nsr,
    const float* __restrict__ s_dst,
    f32x4* __restrict__ out4) {
  int i = blockIdx.x * blockDim.x + threadIdx.x;
  if (i >= NE / 8) return;
  int4 ra = row4[2 * i], rb = row4[2 * i + 1];
  int4 ca = col4[2 * i], cb = col4[2 * i + 1];
  f32x4 oa, ob;
#define OUT_ONE(dst, r, c)                            \
  {                                                   \
    float2 v = nsr[(r)];                              \
    float a = v.x + s_dst[(c)];                       \
    a = (a > 0.0f) ? a : NEG_SLOPE * a;               \
    dst = __expf(a) * v.y;                            \
  }
  OUT_ONE(oa.x, ra.x, ca.x) OUT_ONE(oa.y, ra.y, ca.y)
  OUT_ONE(oa.z, ra.z, ca.z) OUT_ONE(oa.w, ra.w, ca.w)
  OUT_ONE(ob.x, rb.x, cb.x) OUT_ONE(ob.y, rb.y, cb.y)
  OUT_ONE(ob.z, rb.z, cb.z) OUT_ONE(ob.w, rb.w, cb.w)
#undef OUT_ONE
  __builtin_nontemporal_store(oa, &out4[2 * i]);
  __builtin_nontemporal_store(ob, &out4[2 * i + 1]);
}

extern "C" void kernel_launch(void* const* d_in, const int* in_sizes, int n_in,
                              void* d_out, int out_size, void* d_ws, size_t ws_size,
                              hipStream_t stream) {
  const float* x   = (const float*)d_in[0];
  const float* att = (const float*)d_in[1];
  const int* ei    = (const int*)d_in[2];  // (2, E): row then col
  const int* row   = ei;
  const int* col   = ei + NE;
  const int4* row4 = (const int4*)row;
  const int4* col4 = (const int4*)col;
  f32x4* out4      = (f32x4*)d_out;  // E floats, final output

  // Workspace (16B-aligned): nsr float2[N] | s_dst f32[N] | partial f32[32][N]
  float2* nsr     = (float2*)d_ws;                    // 800 KB
  float* s_dst    = (float*)(nsr + NN);               // 400 KB
  float* partial  = s_dst + NN;                       // 12.8 MB

  node_scores_kernel<<<1600, 256, 0, stream>>>(x, att, nsr, s_dst);
  dim3 seg_grid(SEG_S, SEG_P);
  segsum_kernel<<<seg_grid, SEG_BLOCK, 0, stream>>>(row, col, nsr, s_dst, partial);
  reduce_kernel<<<(NN / 4 + 255) / 256, 256, 0, stream>>>(partial, nsr);
  edge_out_kernel<<<(NE / 8 + 255) / 256, 256, 0, stream>>>(row4, col4, nsr, s_dst, out4);
}

// Round 9
// 240.837 us; speedup vs baseline: 2.2079x; 1.0137x over previous
//
#include <hip/hip_runtime.h>

#define NN 100000
#define NE 3200000
#define CC 256
#define NEG_SLOPE 0.2f

#define SEG_S 32             // edge slices (non-atomic partials)
#define SEG_P 8              // node partitions
#define PART_SZ 12500        // NN / SEG_P -> 50 KB LDS
#define SEG_BLOCK 1024
#define ESLICE (NE / SEG_S)  // 100000 edges per slice

typedef __attribute__((ext_vector_type(8))) _Float16 half8;
typedef __attribute__((ext_vector_type(4))) float f32x4;
typedef __attribute__((ext_vector_type(4))) int i32x4;

// Kernel A: per-node dual dot products. Grid-stride wave-per-node; att
// fragments hoisted (loaded once per wave).
__global__ __launch_bounds__(256) void node_scores_kernel(
    const float* __restrict__ x,
    const float* __restrict__ att,
    float* __restrict__ s_src,
    float* __restrict__ s_dst) {
  int wave = (blockIdx.x * blockDim.x + threadIdx.x) >> 6;
  int lane = threadIdx.x & 63;
  const int nwaves = (gridDim.x * blockDim.x) >> 6;
  float4 av = ((const float4*)att)[lane];         // att[:C]
  float4 bv = ((const float4*)(att + CC))[lane];  // att[C:]
  for (int node = wave; node < NN; node += nwaves) {
    float4 xv = ((const float4*)(x + (size_t)node * CC))[lane];
    float s0 = xv.x * av.x + xv.y * av.y + xv.z * av.z + xv.w * av.w;
    float s1 = xv.x * bv.x + xv.y * bv.y + xv.z * bv.z + xv.w * bv.w;
#pragma unroll
    for (int off = 32; off > 0; off >>= 1) {
      s0 += __shfl_down(s0, off, 64);
      s1 += __shfl_down(s1, off, 64);
    }
    if (lane == 0) { s_src[node] = s0; s_dst[node] = s1; }
  }
}

// Kernel B: 8 edges/thread: score -> leaky_relu -> exp -> e (fp16).
// e stays NORMALLY cached: segsum re-reads it 8x from L2 (proven capture).
// Softmax max-subtraction cancels algebraically; exp(alpha) fits fp16.
__global__ __launch_bounds__(256) void edge_exp_kernel(
    const int4* __restrict__ row4,
    const int4* __restrict__ col4,
    const float* __restrict__ s_src,
    const float* __restrict__ s_dst,
    half8* __restrict__ e_out) {
  int i = blockIdx.x * blockDim.x + threadIdx.x;
  if (i >= NE / 8) return;
  int4 ra = row4[2 * i], rb = row4[2 * i + 1];
  int4 ca = col4[2 * i], cb = col4[2 * i + 1];
  float a0 = s_src[ra.x] + s_dst[ca.x];
  float a1 = s_src[ra.y] + s_dst[ca.y];
  float a2 = s_src[ra.z] + s_dst[ca.z];
  float a3 = s_src[ra.w] + s_dst[ca.w];
  float a4 = s_src[rb.x] + s_dst[cb.x];
  float a5 = s_src[rb.y] + s_dst[cb.y];
  float a6 = s_src[rb.z] + s_dst[cb.z];
  float a7 = s_src[rb.w] + s_dst[cb.w];
  a0 = (a0 > 0.0f) ? a0 : NEG_SLOPE * a0;
  a1 = (a1 > 0.0f) ? a1 : NEG_SLOPE * a1;
  a2 = (a2 > 0.0f) ? a2 : NEG_SLOPE * a2;
  a3 = (a3 > 0.0f) ? a3 : NEG_SLOPE * a3;
  a4 = (a4 > 0.0f) ? a4 : NEG_SLOPE * a4;
  a5 = (a5 > 0.0f) ? a5 : NEG_SLOPE * a5;
  a6 = (a6 > 0.0f) ? a6 : NEG_SLOPE * a6;
  a7 = (a7 > 0.0f) ? a7 : NEG_SLOPE * a7;
  half8 h;
  h[0] = (_Float16)__expf(a0);
  h[1] = (_Float16)__expf(a1);
  h[2] = (_Float16)__expf(a2);
  h[3] = (_Float16)__expf(a3);
  h[4] = (_Float16)__expf(a4);
  h[5] = (_Float16)__expf(a5);
  h[6] = (_Float16)__expf(a6);
  h[7] = (_Float16)__expf(a7);
  e_out[i] = h;
}

// Kernel C: atomic-free segment sum, stream-only inner loop (no gathers).
// Block (s,p): stream slice s (row + e-f16, coalesced), LDS-add rows in
// partition p, write the tile as a NON-atomic fp16 partial.
// s fastest in grid -> the 8 partition-siblings of a slice get linear ids
// == s (mod 8) -> same XCD -> slice re-reads are L2 hits.
__global__ __launch_bounds__(SEG_BLOCK) void segsum_kernel(
    const int* __restrict__ row,
    const _Float16* __restrict__ e,
    _Float16* __restrict__ partial /* [SEG_S][NN] fp16 */) {
  __shared__ float tile[PART_SZ];
  const int s = blockIdx.x;  // slice
  const int p = blockIdx.y;  // node partition
  for (int i = threadIdx.x; i < PART_SZ; i += SEG_BLOCK) tile[i] = 0.0f;
  __syncthreads();
  const int lo = p * PART_SZ;
  const int4*  row4s = (const int4*)(row + s * ESLICE);
  const half8* e8    = (const half8*)(e + (size_t)s * ESLICE);
  for (int i = threadIdx.x; i < ESLICE / 8; i += SEG_BLOCK) {
    int4 ra = row4s[2 * i], rb = row4s[2 * i + 1];
    half8 ev = e8[i];
    int r0 = ra.x - lo; if ((unsigned)r0 < PART_SZ) atomicAdd(&tile[r0], (float)ev[0]);
    int r1 = ra.y - lo; if ((unsigned)r1 < PART_SZ) atomicAdd(&tile[r1], (float)ev[1]);
    int r2 = ra.z - lo; if ((unsigned)r2 < PART_SZ) atomicAdd(&tile[r2], (float)ev[2]);
    int r3 = ra.w - lo; if ((unsigned)r3 < PART_SZ) atomicAdd(&tile[r3], (float)ev[3]);
    int r4 = rb.x - lo; if ((unsigned)r4 < PART_SZ) atomicAdd(&tile[r4], (float)ev[4]);
    int r5 = rb.y - lo; if ((unsigned)r5 < PART_SZ) atomicAdd(&tile[r5], (float)ev[5]);
    int r6 = rb.z - lo; if ((unsigned)r6 < PART_SZ) atomicAdd(&tile[r6], (float)ev[6]);
    int r7 = rb.w - lo; if ((unsigned)r7 < PART_SZ) atomicAdd(&tile[r7], (float)ev[7]);
  }
  __syncthreads();
  _Float16* outp = partial + (size_t)s * NN + lo;
  for (int i = threadIdx.x; i < PART_SZ; i += SEG_BLOCK)
    outp[i] = (_Float16)tile[i];
}

// Kernel D: fold 32 fp16 slice-partials (half8 nontemporal loads — read
// once, don't pollute L2), store reciprocal denom (fp32).
__global__ __launch_bounds__(256) void reduce_kernel(
    const _Float16* __restrict__ partial,
    float* __restrict__ rdenom) {
  int n8 = blockIdx.x * blockDim.x + threadIdx.x;
  if (n8 >= NN / 8) return;
  float sum[8] = {0, 0, 0, 0, 0, 0, 0, 0};
#pragma unroll
  for (int s = 0; s < SEG_S; ++s) {
    half8 v = __builtin_nontemporal_load(
        &((const half8*)(partial + (size_t)s * NN))[n8]);
#pragma unroll
    for (int k = 0; k < 8; ++k) sum[k] += (float)v[k];
  }
  int n = 8 * n8;
#pragma unroll
  for (int k = 0; k < 8; ++k) rdenom[n + k] = 1.0f / sum[k];
}

// Kernel E: 8 edges/thread: normalize e (fp16) into fp32 out.
// row/e are last-use here -> nontemporal loads; out never re-read ->
// nontemporal stores. rdenom gathers stay cached (reused across edges).
__global__ __launch_bounds__(256) void edge_div_kernel(
    const i32x4* __restrict__ row4,
    const half8* __restrict__ e,
    const float* __restrict__ rdenom,
    f32x4* __restrict__ out4) {
  int i = blockIdx.x * blockDim.x + threadIdx.x;
  if (i >= NE / 8) return;
  i32x4 ra = __builtin_nontemporal_load(&row4[2 * i]);
  i32x4 rb = __builtin_nontemporal_load(&row4[2 * i + 1]);
  half8 ev = __builtin_nontemporal_load(&e[i]);
  f32x4 oa, ob;
  oa.x = (float)ev[0] * rdenom[ra.x];
  oa.y = (float)ev[1] * rdenom[ra.y];
  oa.z = (float)ev[2] * rdenom[ra.z];
  oa.w = (float)ev[3] * rdenom[ra.w];
  ob.x = (float)ev[4] * rdenom[rb.x];
  ob.y = (float)ev[5] * rdenom[rb.y];
  ob.z = (float)ev[6] * rdenom[rb.z];
  ob.w = (float)ev[7] * rdenom[rb.w];
  __builtin_nontemporal_store(oa, &out4[2 * i]);
  __builtin_nontemporal_store(ob, &out4[2 * i + 1]);
}

extern "C" void kernel_launch(void* const* d_in, const int* in_sizes, int n_in,
                              void* d_out, int out_size, void* d_ws, size_t ws_size,
                              hipStream_t stream) {
  const float* x   = (const float*)d_in[0];
  const float* att = (const float*)d_in[1];
  const int* ei    = (const int*)d_in[2];  // (2, E): row then col
  const int* row   = ei;
  const int4* row4 = (const int4*)row;
  const int4* col4 = (const int4*)(ei + NE);
  f32x4* out4      = (f32x4*)d_out;  // E floats, final output

  // Workspace (16B-aligned):
  float* s_src     = (float*)d_ws;                       // N f32
  float* s_dst     = s_src + NN;                         // N f32
  float* rdenom    = s_dst + NN;                         // N f32
  _Float16* e_buf  = (_Float16*)(rdenom + NN);           // E f16 (6.4 MB)
  _Float16* partial = e_buf + NE;                        // SEG_S*N f16 (6.4 MB)

  node_scores_kernel<<<1600, 256, 0, stream>>>(x, att, s_src, s_dst);
  edge_exp_kernel<<<(NE / 8 + 255) / 256, 256, 0, stream>>>(
      row4, col4, s_src, s_dst, (half8*)e_buf);
  dim3 seg_grid(SEG_S, SEG_P);
  segsum_kernel<<<seg_grid, SEG_BLOCK, 0, stream>>>(row, e_buf, partial);
  reduce_kernel<<<(NN / 8 + 255) / 256, 256, 0, stream>>>(partial, rdenom);
  edge_div_kernel<<<(NE / 8 + 255) / 256, 256, 0, stream>>>(
      (const i32x4*)row4, (const half8*)e_buf, rdenom, out4);
}